// Round 4
// baseline (5389.812 us; speedup 1.0000x reference)
//
#include <hip/hip_runtime.h>
#include <hip/hip_bf16.h>
#include <stdint.h>

// Problem dims (fixed by reference)
#define N_USERS  50000
#define N_ITEMS  100000
#define N_GROUPS 20000
#define DIM      128
#define TWO_DIM  256
#define N_FULL   (N_USERS + N_ITEMS)   // 150000

// Bucketing: 64 rows per bucket
#define BROW     64
#define NB_U     ((N_GROUPS + BROW - 1) / BROW)   // 313
#define NB_I     ((N_GROUPS + BROW - 1) / BROW)   // 313
#define NB_F     ((N_FULL   + BROW - 1) / BROW)   // 2344
#define NB_TOT   (NB_U + NB_I + NB_F)             // 2970
#define CURS     16                                // ints per counter (line-padded)

// ---------------------------------------------------------------------------
// Fallback path (R1): SpMM scatter with f32 atomics.
// ---------------------------------------------------------------------------
__global__ __launch_bounds__(256) void spmm_atomic(
    const int* __restrict__ rows, const int* __restrict__ cols,
    const float* __restrict__ vals, const float* __restrict__ dense,
    float* __restrict__ out, int nnz)
{
    long long t = (long long)blockIdx.x * blockDim.x + threadIdx.x;
    int e    = (int)(t >> 5);
    int lane = (int)(t & 31);
    if (e >= nnz) return;
    int   r = rows[e];
    int   c = cols[e];
    float v = vals[e];
    float4 x = ((const float4*)(dense + (size_t)c * DIM))[lane];
    float* dst = out + (size_t)r * DIM + lane * 4;
    atomicAdd(dst + 0, v * x.x);
    atomicAdd(dst + 1, v * x.y);
    atomicAdd(dst + 2, v * x.z);
    atomicAdd(dst + 3, v * x.w);
}

// ---------------------------------------------------------------------------
// Bucket histogram: LDS-privatized per block, flushed to line-padded counters.
// ---------------------------------------------------------------------------
__global__ __launch_bounds__(256) void hist_buckets(
    const int* __restrict__ u_rows, int nnz_u,
    const int* __restrict__ i_rows, int nnz_i,
    const int* __restrict__ f_rows, int nnz_f,
    int* __restrict__ cnt)
{
    __shared__ int h[NB_TOT];
    for (int i = threadIdx.x; i < NB_TOT; i += 256) h[i] = 0;
    __syncthreads();
    long long total  = (long long)nnz_u + nnz_i + nnz_f;
    long long stride = (long long)gridDim.x * blockDim.x;
    for (long long t = (long long)blockIdx.x * blockDim.x + threadIdx.x;
         t < total; t += stride) {
        int b;
        if (t < nnz_u)                          b = u_rows[t] >> 6;
        else if (t < (long long)nnz_u + nnz_i)  b = NB_U + (i_rows[t - nnz_u] >> 6);
        else                                    b = NB_U + NB_I + (f_rows[t - nnz_u - nnz_i] >> 6);
        atomicAdd(&h[b], 1);
    }
    __syncthreads();
    for (int i = threadIdx.x; i < NB_TOT; i += 256)
        if (h[i]) atomicAdd(&cnt[i * CURS], h[i]);
}

// ---------------------------------------------------------------------------
// Single-block exclusive scan over NB_TOT line-padded counts.
// In-place: cnt[b*CURS] becomes the scatter cursor; ptr[b] = start, ptr[NB]=total.
// ---------------------------------------------------------------------------
__global__ __launch_bounds__(256) void scan_buckets(
    int* __restrict__ cnt, int* __restrict__ ptr)
{
    __shared__ int wsum[4];
    __shared__ int s_carry;
    int tid = threadIdx.x, lane = tid & 63, wave = tid >> 6;
    if (tid == 0) s_carry = 0;
    __syncthreads();
    for (int base = 0; base < NB_TOT; base += 256) {
        int b = base + tid;
        int x = (b < NB_TOT) ? cnt[b * CURS] : 0;
        int incl = x;
#pragma unroll
        for (int off = 1; off < 64; off <<= 1) {
            int y = __shfl_up(incl, off, 64);
            if (lane >= off) incl += y;
        }
        if (lane == 63) wsum[wave] = incl;
        __syncthreads();
        int waveOff = 0;
        for (int w = 0; w < wave; ++w) waveOff += wsum[w];
        int carry = s_carry;
        int ex = carry + waveOff + incl - x;
        if (b < NB_TOT) { cnt[b * CURS] = ex; ptr[b] = ex; }
        __syncthreads();
        if (tid == 255) s_carry = carry + waveOff + incl;
        __syncthreads();
    }
    if (tid == 0) ptr[NB_TOT] = s_carry;
}

// ---------------------------------------------------------------------------
// Bucketed scatter: append (lrow<<17 | col, val) to the bucket's region.
// Cursor lines stay hot in L2; append frontier lines fill before eviction.
// ---------------------------------------------------------------------------
__global__ __launch_bounds__(256) void scatter_buckets(
    const int* __restrict__ u_rows, const int* __restrict__ u_cols,
    const float* __restrict__ u_vals, int nnz_u,
    const int* __restrict__ i_rows, const int* __restrict__ i_cols,
    const float* __restrict__ i_vals, int nnz_i,
    const int* __restrict__ f_rows, const int* __restrict__ f_cols,
    const float* __restrict__ f_vals, int nnz_f,
    int* __restrict__ cursor, uint2* __restrict__ pack)
{
    long long t = (long long)blockIdx.x * blockDim.x + threadIdx.x;
    int b, lrow, col; float v;
    if (t < nnz_u) {
        int e = (int)t; int r = u_rows[e];
        b = r >> 6; lrow = r & 63; col = u_cols[e]; v = u_vals[e];
    } else if (t < (long long)nnz_u + nnz_i) {
        int e = (int)(t - nnz_u); int r = i_rows[e];
        b = NB_U + (r >> 6); lrow = r & 63; col = i_cols[e]; v = i_vals[e];
    } else if (t < (long long)nnz_u + nnz_i + nnz_f) {
        int e = (int)(t - nnz_u - nnz_i); int r = f_rows[e];
        b = NB_U + NB_I + (r >> 6); lrow = r & 63; col = f_cols[e]; v = f_vals[e];
    } else return;
    int p = atomicAdd(&cursor[b * CURS], 1);
    pack[p] = make_uint2(((unsigned)lrow << 17) | (unsigned)col, __float_as_uint(v));
}

// ---------------------------------------------------------------------------
// Fused sort-free SpMM: one block per 64-row bucket, LDS f32 accumulators in
// plane layout acc[c][lrow][slot] (conflict-free), LDS atomics for the adds.
// Handles two segments (A then B) so u+i can share one launch.
// ---------------------------------------------------------------------------
__global__ __launch_bounds__(256) void spmm_bucket(
    const int* __restrict__ ptr, const uint2* __restrict__ pack,
    const float4* __restrict__ denseA, float* __restrict__ outA, int nbA, int nrowsA,
    const float4* __restrict__ denseB, float* __restrict__ outB, int nrowsB,
    int bucket_base)
{
    __shared__ float acc[4][BROW][32];   // 32 KB
    int bl = blockIdx.x;
    const float4* dense; float* out; int nrows; int lb;
    if (bl < nbA) { dense = denseA; out = outA; nrows = nrowsA; lb = bl; }
    else          { dense = denseB; out = outB; nrows = nrowsB; lb = bl - nbA; }
    int rowBase = lb * BROW;
    int bid = bucket_base + bl;
    int tid = threadIdx.x;

    float* af = &acc[0][0][0];
    for (int i = tid; i < 4 * BROW * 32; i += 256) af[i] = 0.f;

    int p0 = ptr[bid], p1 = ptr[bid + 1];
    int wave = tid >> 6, lane = tid & 63, half = (lane >> 5) & 1, sl = lane & 31;
    __syncthreads();

    // 4 waves x 8 edges per iteration; each wave-half owns one edge of a pair;
    // 4 edge-pairs unrolled -> 4 outstanding 16B gathers per lane.
    for (int base = p0 + wave * 8; base < p1; base += 32) {
        int j0 = base + 0 + half, j1 = base + 2 + half;
        int j2 = base + 4 + half, j3 = base + 6 + half;
        uint2 e0 = (j0 < p1) ? pack[j0] : make_uint2(0u, 0u);
        uint2 e1 = (j1 < p1) ? pack[j1] : make_uint2(0u, 0u);
        uint2 e2 = (j2 < p1) ? pack[j2] : make_uint2(0u, 0u);
        uint2 e3 = (j3 < p1) ? pack[j3] : make_uint2(0u, 0u);
        float4 x0 = dense[(size_t)(e0.x & 0x1FFFF) * 32 + sl];
        float4 x1 = dense[(size_t)(e1.x & 0x1FFFF) * 32 + sl];
        float4 x2 = dense[(size_t)(e2.x & 0x1FFFF) * 32 + sl];
        float4 x3 = dense[(size_t)(e3.x & 0x1FFFF) * 32 + sl];
        {
            int r = e0.x >> 17; float v = __uint_as_float(e0.y);
            atomicAdd(&acc[0][r][sl], v * x0.x);
            atomicAdd(&acc[1][r][sl], v * x0.y);
            atomicAdd(&acc[2][r][sl], v * x0.z);
            atomicAdd(&acc[3][r][sl], v * x0.w);
        }
        {
            int r = e1.x >> 17; float v = __uint_as_float(e1.y);
            atomicAdd(&acc[0][r][sl], v * x1.x);
            atomicAdd(&acc[1][r][sl], v * x1.y);
            atomicAdd(&acc[2][r][sl], v * x1.z);
            atomicAdd(&acc[3][r][sl], v * x1.w);
        }
        {
            int r = e2.x >> 17; float v = __uint_as_float(e2.y);
            atomicAdd(&acc[0][r][sl], v * x2.x);
            atomicAdd(&acc[1][r][sl], v * x2.y);
            atomicAdd(&acc[2][r][sl], v * x2.z);
            atomicAdd(&acc[3][r][sl], v * x2.w);
        }
        {
            int r = e3.x >> 17; float v = __uint_as_float(e3.y);
            atomicAdd(&acc[0][r][sl], v * x3.x);
            atomicAdd(&acc[1][r][sl], v * x3.y);
            atomicAdd(&acc[2][r][sl], v * x3.z);
            atomicAdd(&acc[3][r][sl], v * x3.w);
        }
    }
    __syncthreads();

    // coalesced write-out
    float4* out4 = (float4*)out;
    for (int idx = tid; idx < BROW * 32; idx += 256) {
        int lr = idx >> 5, s = idx & 31;
        int row = rowBase + lr;
        if (row < nrows) {
            float4 o = make_float4(acc[0][lr][s], acc[1][lr][s],
                                   acc[2][lr][s], acc[3][lr][s]);
            out4[(size_t)row * 32 + s] = o;
        }
    }
}

// ---------------------------------------------------------------------------
// Dense layer: msg[g, d] = b[d] + sum_k concat(um,im)[g, k] * W[d, k]
// ---------------------------------------------------------------------------
__global__ __launch_bounds__(256) void dense_agg(
    const float* __restrict__ um, const float* __restrict__ im,
    const float* __restrict__ W, const float* __restrict__ b,
    float* __restrict__ msg)
{
    __shared__ float As[32][68];
    __shared__ float Ws[64][132];

    int tid = threadIdx.x;
    int tx  = tid & 15;
    int ty  = tid >> 4;
    int rowBase = blockIdx.x * 32;

    float acc[2][8];
#pragma unroll
    for (int i = 0; i < 2; ++i)
#pragma unroll
        for (int j = 0; j < 8; ++j) acc[i][j] = 0.f;

    for (int kc = 0; kc < 4; ++kc) {
        int k0 = kc * 64;
        const float* Asrc = (k0 < DIM) ? um : im;
        int kOff = (k0 < DIM) ? k0 : (k0 - DIM);

#pragma unroll
        for (int l = 0; l < 2; ++l) {
            int idx = tid + l * 256;
            int r   = idx >> 4;
            int kq  = idx & 15;
            int gRow = rowBase + r;
            float4 v = make_float4(0.f, 0.f, 0.f, 0.f);
            if (gRow < N_GROUPS)
                v = *(const float4*)(Asrc + (size_t)gRow * DIM + kOff + kq * 4);
            *(float4*)&As[r][kq * 4] = v;
        }
#pragma unroll
        for (int l = 0; l < 8; ++l) {
            int idx = tid + l * 256;
            int d   = idx >> 4;
            int kq  = idx & 15;
            float4 v = *(const float4*)(W + (size_t)d * TWO_DIM + k0 + kq * 4);
            Ws[kq * 4 + 0][d] = v.x;
            Ws[kq * 4 + 1][d] = v.y;
            Ws[kq * 4 + 2][d] = v.z;
            Ws[kq * 4 + 3][d] = v.w;
        }
        __syncthreads();

        int ty2 = ty * 2;
        int tx8 = tx * 8;
#pragma unroll 8
        for (int k = 0; k < 64; ++k) {
            float a0 = As[ty2 + 0][k];
            float a1 = As[ty2 + 1][k];
            float4 w0 = *(const float4*)&Ws[k][tx8];
            float4 w1 = *(const float4*)&Ws[k][tx8 + 4];
            acc[0][0] = fmaf(a0, w0.x, acc[0][0]);
            acc[0][1] = fmaf(a0, w0.y, acc[0][1]);
            acc[0][2] = fmaf(a0, w0.z, acc[0][2]);
            acc[0][3] = fmaf(a0, w0.w, acc[0][3]);
            acc[0][4] = fmaf(a0, w1.x, acc[0][4]);
            acc[0][5] = fmaf(a0, w1.y, acc[0][5]);
            acc[0][6] = fmaf(a0, w1.z, acc[0][6]);
            acc[0][7] = fmaf(a0, w1.w, acc[0][7]);
            acc[1][0] = fmaf(a1, w0.x, acc[1][0]);
            acc[1][1] = fmaf(a1, w0.y, acc[1][1]);
            acc[1][2] = fmaf(a1, w0.z, acc[1][2]);
            acc[1][3] = fmaf(a1, w0.w, acc[1][3]);
            acc[1][4] = fmaf(a1, w1.x, acc[1][4]);
            acc[1][5] = fmaf(a1, w1.y, acc[1][5]);
            acc[1][6] = fmaf(a1, w1.z, acc[1][6]);
            acc[1][7] = fmaf(a1, w1.w, acc[1][7]);
        }
        __syncthreads();
    }

    int d0 = tx * 8;
    float4 bv0 = *(const float4*)(b + d0);
    float4 bv1 = *(const float4*)(b + d0 + 4);
#pragma unroll
    for (int i = 0; i < 2; ++i) {
        int gRow = rowBase + ty * 2 + i;
        if (gRow < N_GROUPS) {
            float4 o0 = make_float4(acc[i][0] + bv0.x, acc[i][1] + bv0.y,
                                    acc[i][2] + bv0.z, acc[i][3] + bv0.w);
            float4 o1 = make_float4(acc[i][4] + bv1.x, acc[i][5] + bv1.y,
                                    acc[i][6] + bv1.z, acc[i][7] + bv1.w);
            *(float4*)(msg + (size_t)gRow * DIM + d0)     = o0;
            *(float4*)(msg + (size_t)gRow * DIM + d0 + 4) = o1;
        }
    }
}

// ---------------------------------------------------------------------------
extern "C" void kernel_launch(void* const* d_in, const int* in_sizes, int n_in,
                              void* d_out, int out_size, void* d_ws, size_t ws_size,
                              hipStream_t stream)
{
    const float* user_emb = (const float*)d_in[0];
    const float* item_emb = (const float*)d_in[1];
    const int*   u_rows = (const int*)d_in[3];
    const int*   u_cols = (const int*)d_in[4];
    const float* u_vals = (const float*)d_in[5];
    const int*   i_rows = (const int*)d_in[6];
    const int*   i_cols = (const int*)d_in[7];
    const float* i_vals = (const float*)d_in[8];
    const int*   f_rows = (const int*)d_in[9];
    const int*   f_cols = (const int*)d_in[10];
    const float* f_vals = (const float*)d_in[11];
    const float* W      = (const float*)d_in[12];
    const float* bias   = (const float*)d_in[13];

    int nnz_u = in_sizes[3];
    int nnz_i = in_sizes[6];
    int nnz_f = in_sizes[9];
    long long nnz_tot = (long long)nnz_u + nnz_i + nnz_f;

    float* out  = (float*)d_out;
    float* norm = out;                                   // [150000, 128]
    float* msg  = out + (size_t)N_FULL * DIM;            // [20000, 128]

    // um/im scratch in the norm region (fully overwritten by the f-phase)
    float* um = norm;
    float* im = norm + (size_t)N_GROUPS * DIM;

    auto ceil16 = [](size_t b) { return (b + 15) & ~(size_t)15; };
    size_t need = 0;
    size_t o_cnt  = need; need += ceil16((size_t)NB_TOT * CURS * 4);
    size_t o_ptr  = need; need += ceil16((size_t)(NB_TOT + 1) * 4);
    size_t o_pack = need; need += ceil16((size_t)nnz_tot * 8);

    auto eblocks = [](long long n) { return (unsigned)((n + 255) / 256); };

    if (ws_size >= need) {
        uint8_t* ws = (uint8_t*)d_ws;
        int*   cnt  = (int*)(ws + o_cnt);     // doubles as cursor after scan
        int*   ptr  = (int*)(ws + o_ptr);
        uint2* pack = (uint2*)(ws + o_pack);

        hipMemsetAsync(cnt, 0, (size_t)NB_TOT * CURS * 4, stream);

        hist_buckets<<<1024, 256, 0, stream>>>(
            u_rows, nnz_u, i_rows, nnz_i, f_rows, nnz_f, cnt);

        scan_buckets<<<1, 256, 0, stream>>>(cnt, ptr);

        scatter_buckets<<<eblocks(nnz_tot), 256, 0, stream>>>(
            u_rows, u_cols, u_vals, nnz_u,
            i_rows, i_cols, i_vals, nnz_i,
            f_rows, f_cols, f_vals, nnz_f,
            cnt, pack);

        // u + i SpMM (fused launch, one block per 64-row bucket)
        spmm_bucket<<<NB_U + NB_I, 256, 0, stream>>>(
            ptr, pack,
            (const float4*)user_emb, um, NB_U, N_GROUPS,
            (const float4*)item_emb, im, N_GROUPS, 0);

        dense_agg<<<(N_GROUPS + 31) / 32, 256, 0, stream>>>(um, im, W, bias, msg);

        // f SpMM -> norm (overwrites scratch region)
        spmm_bucket<<<NB_F, 256, 0, stream>>>(
            ptr, pack,
            (const float4*)msg, norm, NB_F, N_FULL,
            (const float4*)msg, norm, N_FULL, NB_U + NB_I);
    } else {
        // Fallback: R1 atomic path
        hipMemsetAsync(norm, 0, (size_t)N_FULL * DIM * sizeof(float), stream);
        auto spmm_blocks = [](int nnz) {
            return (unsigned)(((long long)nnz * 32 + 255) / 256);
        };
        spmm_atomic<<<spmm_blocks(nnz_u), 256, 0, stream>>>(
            u_rows, u_cols, u_vals, user_emb, um, nnz_u);
        spmm_atomic<<<spmm_blocks(nnz_i), 256, 0, stream>>>(
            i_rows, i_cols, i_vals, item_emb, im, nnz_i);
        dense_agg<<<(N_GROUPS + 31) / 32, 256, 0, stream>>>(um, im, W, bias, msg);
        hipMemsetAsync(norm, 0, (size_t)2 * N_GROUPS * DIM * sizeof(float), stream);
        spmm_atomic<<<spmm_blocks(nnz_f), 256, 0, stream>>>(
            f_rows, f_cols, f_vals, msg, norm, nnz_f);
    }
}

// Round 5
// 1080.966 us; speedup vs baseline: 4.9861x; 4.9861x over previous
//
#include <hip/hip_runtime.h>
#include <hip/hip_bf16.h>
#include <stdint.h>

// Problem dims (fixed by reference)
#define N_USERS  50000
#define N_ITEMS  100000
#define N_GROUPS 20000
#define DIM      128
#define TWO_DIM  256
#define N_FULL   (N_USERS + N_ITEMS)   // 150000

// Buckets sized for ~1600 edges each (mean): u=32 rows, i=16, f=64.
#define NBU  625                        // 20000/32
#define NBI  1250                       // 20000/16
#define NBF  2344                       // ceil(150000/64)
#define NBT  (NBU + NBI + NBF)          // 4219
#define CURS 16                         // ints per cursor (line-padded)
#define CAP  2048                       // max edges staged per bucket (mean 1600, sigma ~40)

// ---------------------------------------------------------------------------
// Fallback path (R1): SpMM scatter with f32 atomics.
// ---------------------------------------------------------------------------
__global__ __launch_bounds__(256) void spmm_atomic(
    const int* __restrict__ rows, const int* __restrict__ cols,
    const float* __restrict__ vals, const float* __restrict__ dense,
    float* __restrict__ out, int nnz)
{
    long long t = (long long)blockIdx.x * blockDim.x + threadIdx.x;
    int e    = (int)(t >> 5);
    int lane = (int)(t & 31);
    if (e >= nnz) return;
    int   r = rows[e];
    int   c = cols[e];
    float v = vals[e];
    float4 x = ((const float4*)(dense + (size_t)c * DIM))[lane];
    float* dst = out + (size_t)r * DIM + lane * 4;
    atomicAdd(dst + 0, v * x.x);
    atomicAdd(dst + 1, v * x.y);
    atomicAdd(dst + 2, v * x.z);
    atomicAdd(dst + 3, v * x.w);
}

// ---------------------------------------------------------------------------
// Bucket id / local row mapping
//   u: b = r>>5          lrow = r&31
//   i: b = NBU + (r>>4)  lrow = r&15
//   f: b = NBU+NBI+(r>>6) lrow = r&63
// ---------------------------------------------------------------------------

// Bucket histogram: LDS-privatized per block, flushed to line-padded counters.
__global__ __launch_bounds__(256) void hist_buckets(
    const int* __restrict__ u_rows, int nnz_u,
    const int* __restrict__ i_rows, int nnz_i,
    const int* __restrict__ f_rows, int nnz_f,
    int* __restrict__ cnt)
{
    __shared__ int h[NBT];
    for (int i = threadIdx.x; i < NBT; i += 256) h[i] = 0;
    __syncthreads();
    long long total  = (long long)nnz_u + nnz_i + nnz_f;
    long long stride = (long long)gridDim.x * blockDim.x;
    for (long long t = (long long)blockIdx.x * blockDim.x + threadIdx.x;
         t < total; t += stride) {
        int b;
        if (t < nnz_u)                          b = u_rows[t] >> 5;
        else if (t < (long long)nnz_u + nnz_i)  b = NBU + (i_rows[t - nnz_u] >> 4);
        else                                    b = NBU + NBI + (f_rows[t - nnz_u - nnz_i] >> 6);
        atomicAdd(&h[b], 1);
    }
    __syncthreads();
    for (int i = threadIdx.x; i < NBT; i += 256)
        if (h[i]) atomicAdd(&cnt[i * CURS], h[i]);
}

// Single-block exclusive scan over NBT line-padded counts.
// In-place: cnt[b*CURS] becomes scatter cursor; bptr[b] = start, bptr[NBT]=total.
__global__ __launch_bounds__(256) void scan_buckets(
    int* __restrict__ cnt, int* __restrict__ bptr)
{
    __shared__ int wsum[4];
    __shared__ int s_carry;
    int tid = threadIdx.x, lane = tid & 63, wave = tid >> 6;
    if (tid == 0) s_carry = 0;
    __syncthreads();
    for (int base = 0; base < NBT; base += 256) {
        int b = base + tid;
        int x = (b < NBT) ? cnt[b * CURS] : 0;
        int incl = x;
#pragma unroll
        for (int off = 1; off < 64; off <<= 1) {
            int y = __shfl_up(incl, off, 64);
            if (lane >= off) incl += y;
        }
        if (lane == 63) wsum[wave] = incl;
        __syncthreads();
        int waveOff = 0;
        for (int w = 0; w < wave; ++w) waveOff += wsum[w];
        int carry = s_carry;
        int ex = carry + waveOff + incl - x;
        if (b < NBT) { cnt[b * CURS] = ex; bptr[b] = ex; }
        __syncthreads();
        if (tid == 255) s_carry = carry + waveOff + incl;
        __syncthreads();
    }
    if (tid == 0) bptr[NBT] = s_carry;
}

// Bucketed scatter: append (lrow<<17 | col, val). Append frontier is
// spatially+temporally adjacent -> lines fill before eviction.
__global__ __launch_bounds__(256) void scatter_buckets(
    const int* __restrict__ u_rows, const int* __restrict__ u_cols,
    const float* __restrict__ u_vals, int nnz_u,
    const int* __restrict__ i_rows, const int* __restrict__ i_cols,
    const float* __restrict__ i_vals, int nnz_i,
    const int* __restrict__ f_rows, const int* __restrict__ f_cols,
    const float* __restrict__ f_vals, int nnz_f,
    int* __restrict__ cursor, uint2* __restrict__ pack)
{
    long long t = (long long)blockIdx.x * blockDim.x + threadIdx.x;
    int b, lrow, col; float v;
    if (t < nnz_u) {
        int e = (int)t; int r = u_rows[e];
        b = r >> 5; lrow = r & 31; col = u_cols[e]; v = u_vals[e];
    } else if (t < (long long)nnz_u + nnz_i) {
        int e = (int)(t - nnz_u); int r = i_rows[e];
        b = NBU + (r >> 4); lrow = r & 15; col = i_cols[e]; v = i_vals[e];
    } else if (t < (long long)nnz_u + nnz_i + nnz_f) {
        int e = (int)(t - nnz_u - nnz_i); int r = f_rows[e];
        b = NBU + NBI + (r >> 6); lrow = r & 63; col = f_cols[e]; v = f_vals[e];
    } else return;
    int p = atomicAdd(&cursor[b * CURS], 1);
    pack[p] = make_uint2(((unsigned)lrow << 17) | (unsigned)col, __float_as_uint(v));
}

// ---------------------------------------------------------------------------
// Bucket gather SpMM: one block per bucket.
//  phase1: LDS hist of local rows (bucket edges read from global, L2-hot)
//  phase2: wave-scan -> row offsets; re-read edges, LDS-permute into row order
//  phase3: each wave walks rows with REGISTER accumulators
//          (half-wave per edge, 4 edges in flight, shfl_xor(32) combine)
// Two segments per launch (A then B) so u+i share one dispatch.
// ---------------------------------------------------------------------------
__global__ __launch_bounds__(256) void gather_buckets(
    const int* __restrict__ bptr, const uint2* __restrict__ pack,
    const float4* __restrict__ denseA, float* __restrict__ outA,
    int nbA, int rowsA, int nrowsA, int baseA,
    const float4* __restrict__ denseB, float* __restrict__ outB,
    int rowsB, int nrowsB, int baseB)
{
    __shared__ uint2 sE[CAP];        // 16 KB
    __shared__ int   h[64];          // hist -> cursor
    __shared__ int   o[65];          // row offsets

    const float4* dense; float* out; int rowsPB, nrows, lb, bid;
    if ((int)blockIdx.x < nbA) {
        dense = denseA; out = outA; rowsPB = rowsA; nrows = nrowsA;
        lb = blockIdx.x; bid = baseA + lb;
    } else {
        dense = denseB; out = outB; rowsPB = rowsB; nrows = nrowsB;
        lb = blockIdx.x - nbA; bid = baseB + lb;
    }
    int tid = threadIdx.x;
    if (tid < 64) h[tid] = 0;
    __syncthreads();

    int p0 = bptr[bid], p1 = bptr[bid + 1];
    int cnt = p1 - p0;

    // phase1: histogram local rows
    for (int j = tid; j < cnt; j += 256)
        atomicAdd(&h[pack[p0 + j].x >> 17], 1);
    __syncthreads();

    // phase2a: exclusive scan (wave 0)
    if (tid < 64) {
        int x = (tid < rowsPB) ? h[tid] : 0;
        int incl = x;
#pragma unroll
        for (int off = 1; off < 64; off <<= 1) {
            int y = __shfl_up(incl, off, 64);
            if ((tid & 63) >= off) incl += y;
        }
        o[tid + 1] = incl;
        if (tid == 0) o[0] = 0;
        h[tid] = incl - x;               // exclusive -> cursor
    }
    __syncthreads();

    // phase2b: permute edges into row-sorted LDS order
    for (int j = tid; j < cnt; j += 256) {
        uint2 e = pack[p0 + j];
        int r = e.x >> 17;
        int p = atomicAdd(&h[r], 1);
        sE[p] = make_uint2(e.x & 0x1FFFF, e.y);
    }
    __syncthreads();

    // phase3: register-accumulate per row
    int wave = tid >> 6, lane = tid & 63, half = lane >> 5, sl = lane & 31;
    float4* out4 = (float4*)out;
    for (int r = wave; r < rowsPB; r += 4) {
        int s = o[r], epos = o[r + 1];
        float4 a0 = make_float4(0.f, 0.f, 0.f, 0.f);
        float4 a1 = a0, a2 = a0, a3 = a0;
        for (int base = s; base < epos; base += 8) {
            int j0 = base + half, j1 = base + 2 + half;
            int j2 = base + 4 + half, j3 = base + 6 + half;
            if (j0 < epos) {
                uint2 e = sE[j0]; float v = __uint_as_float(e.y);
                float4 x = dense[(size_t)e.x * 32 + sl];
                a0.x = fmaf(v, x.x, a0.x); a0.y = fmaf(v, x.y, a0.y);
                a0.z = fmaf(v, x.z, a0.z); a0.w = fmaf(v, x.w, a0.w);
            }
            if (j1 < epos) {
                uint2 e = sE[j1]; float v = __uint_as_float(e.y);
                float4 x = dense[(size_t)e.x * 32 + sl];
                a1.x = fmaf(v, x.x, a1.x); a1.y = fmaf(v, x.y, a1.y);
                a1.z = fmaf(v, x.z, a1.z); a1.w = fmaf(v, x.w, a1.w);
            }
            if (j2 < epos) {
                uint2 e = sE[j2]; float v = __uint_as_float(e.y);
                float4 x = dense[(size_t)e.x * 32 + sl];
                a2.x = fmaf(v, x.x, a2.x); a2.y = fmaf(v, x.y, a2.y);
                a2.z = fmaf(v, x.z, a2.z); a2.w = fmaf(v, x.w, a2.w);
            }
            if (j3 < epos) {
                uint2 e = sE[j3]; float v = __uint_as_float(e.y);
                float4 x = dense[(size_t)e.x * 32 + sl];
                a3.x = fmaf(v, x.x, a3.x); a3.y = fmaf(v, x.y, a3.y);
                a3.z = fmaf(v, x.z, a3.z); a3.w = fmaf(v, x.w, a3.w);
            }
        }
        float4 acc;
        acc.x = (a0.x + a1.x) + (a2.x + a3.x);
        acc.y = (a0.y + a1.y) + (a2.y + a3.y);
        acc.z = (a0.z + a1.z) + (a2.z + a3.z);
        acc.w = (a0.w + a1.w) + (a2.w + a3.w);
        acc.x += __shfl_xor(acc.x, 32, 64);
        acc.y += __shfl_xor(acc.y, 32, 64);
        acc.z += __shfl_xor(acc.z, 32, 64);
        acc.w += __shfl_xor(acc.w, 32, 64);
        int row = lb * rowsPB + r;
        if (half == 0 && row < nrows)
            out4[(size_t)row * 32 + sl] = acc;
    }
}

// ---------------------------------------------------------------------------
// Dense layer: msg[g, d] = b[d] + sum_k concat(um,im)[g, k] * W[d, k]
// ---------------------------------------------------------------------------
__global__ __launch_bounds__(256) void dense_agg(
    const float* __restrict__ um, const float* __restrict__ im,
    const float* __restrict__ W, const float* __restrict__ b,
    float* __restrict__ msg)
{
    __shared__ float As[32][68];
    __shared__ float Ws[64][132];

    int tid = threadIdx.x;
    int tx  = tid & 15;
    int ty  = tid >> 4;
    int rowBase = blockIdx.x * 32;

    float acc[2][8];
#pragma unroll
    for (int i = 0; i < 2; ++i)
#pragma unroll
        for (int j = 0; j < 8; ++j) acc[i][j] = 0.f;

    for (int kc = 0; kc < 4; ++kc) {
        int k0 = kc * 64;
        const float* Asrc = (k0 < DIM) ? um : im;
        int kOff = (k0 < DIM) ? k0 : (k0 - DIM);

#pragma unroll
        for (int l = 0; l < 2; ++l) {
            int idx = tid + l * 256;
            int r   = idx >> 4;
            int kq  = idx & 15;
            int gRow = rowBase + r;
            float4 v = make_float4(0.f, 0.f, 0.f, 0.f);
            if (gRow < N_GROUPS)
                v = *(const float4*)(Asrc + (size_t)gRow * DIM + kOff + kq * 4);
            *(float4*)&As[r][kq * 4] = v;
        }
#pragma unroll
        for (int l = 0; l < 8; ++l) {
            int idx = tid + l * 256;
            int d   = idx >> 4;
            int kq  = idx & 15;
            float4 v = *(const float4*)(W + (size_t)d * TWO_DIM + k0 + kq * 4);
            Ws[kq * 4 + 0][d] = v.x;
            Ws[kq * 4 + 1][d] = v.y;
            Ws[kq * 4 + 2][d] = v.z;
            Ws[kq * 4 + 3][d] = v.w;
        }
        __syncthreads();

        int ty2 = ty * 2;
        int tx8 = tx * 8;
#pragma unroll 8
        for (int k = 0; k < 64; ++k) {
            float a0 = As[ty2 + 0][k];
            float a1 = As[ty2 + 1][k];
            float4 w0 = *(const float4*)&Ws[k][tx8];
            float4 w1 = *(const float4*)&Ws[k][tx8 + 4];
            acc[0][0] = fmaf(a0, w0.x, acc[0][0]);
            acc[0][1] = fmaf(a0, w0.y, acc[0][1]);
            acc[0][2] = fmaf(a0, w0.z, acc[0][2]);
            acc[0][3] = fmaf(a0, w0.w, acc[0][3]);
            acc[0][4] = fmaf(a0, w1.x, acc[0][4]);
            acc[0][5] = fmaf(a0, w1.y, acc[0][5]);
            acc[0][6] = fmaf(a0, w1.z, acc[0][6]);
            acc[0][7] = fmaf(a0, w1.w, acc[0][7]);
            acc[1][0] = fmaf(a1, w0.x, acc[1][0]);
            acc[1][1] = fmaf(a1, w0.y, acc[1][1]);
            acc[1][2] = fmaf(a1, w0.z, acc[1][2]);
            acc[1][3] = fmaf(a1, w0.w, acc[1][3]);
            acc[1][4] = fmaf(a1, w1.x, acc[1][4]);
            acc[1][5] = fmaf(a1, w1.y, acc[1][5]);
            acc[1][6] = fmaf(a1, w1.z, acc[1][6]);
            acc[1][7] = fmaf(a1, w1.w, acc[1][7]);
        }
        __syncthreads();
    }

    int d0 = tx * 8;
    float4 bv0 = *(const float4*)(b + d0);
    float4 bv1 = *(const float4*)(b + d0 + 4);
#pragma unroll
    for (int i = 0; i < 2; ++i) {
        int gRow = rowBase + ty * 2 + i;
        if (gRow < N_GROUPS) {
            float4 o0 = make_float4(acc[i][0] + bv0.x, acc[i][1] + bv0.y,
                                    acc[i][2] + bv0.z, acc[i][3] + bv0.w);
            float4 o1 = make_float4(acc[i][4] + bv1.x, acc[i][5] + bv1.y,
                                    acc[i][6] + bv1.z, acc[i][7] + bv1.w);
            *(float4*)(msg + (size_t)gRow * DIM + d0)     = o0;
            *(float4*)(msg + (size_t)gRow * DIM + d0 + 4) = o1;
        }
    }
}

// ---------------------------------------------------------------------------
extern "C" void kernel_launch(void* const* d_in, const int* in_sizes, int n_in,
                              void* d_out, int out_size, void* d_ws, size_t ws_size,
                              hipStream_t stream)
{
    const float* user_emb = (const float*)d_in[0];
    const float* item_emb = (const float*)d_in[1];
    const int*   u_rows = (const int*)d_in[3];
    const int*   u_cols = (const int*)d_in[4];
    const float* u_vals = (const float*)d_in[5];
    const int*   i_rows = (const int*)d_in[6];
    const int*   i_cols = (const int*)d_in[7];
    const float* i_vals = (const float*)d_in[8];
    const int*   f_rows = (const int*)d_in[9];
    const int*   f_cols = (const int*)d_in[10];
    const float* f_vals = (const float*)d_in[11];
    const float* W      = (const float*)d_in[12];
    const float* bias   = (const float*)d_in[13];

    int nnz_u = in_sizes[3];
    int nnz_i = in_sizes[6];
    int nnz_f = in_sizes[9];
    long long nnz_tot = (long long)nnz_u + nnz_i + nnz_f;

    float* out  = (float*)d_out;
    float* norm = out;                                   // [150000, 128]
    float* msg  = out + (size_t)N_FULL * DIM;            // [20000, 128]

    // um/im scratch in the norm region (fully overwritten by the f-phase)
    float* um = norm;
    float* im = norm + (size_t)N_GROUPS * DIM;

    auto ceil16 = [](size_t b) { return (b + 15) & ~(size_t)15; };
    size_t need = 0;
    size_t o_cnt  = need; need += ceil16((size_t)NBT * CURS * 4);
    size_t o_bptr = need; need += ceil16((size_t)(NBT + 1) * 4);
    size_t o_pack = need; need += ceil16((size_t)nnz_tot * 8);

    auto eblocks = [](long long n) { return (unsigned)((n + 255) / 256); };

    if (ws_size >= need) {
        uint8_t* ws = (uint8_t*)d_ws;
        int*   cnt  = (int*)(ws + o_cnt);     // doubles as cursor after scan
        int*   bptr = (int*)(ws + o_bptr);
        uint2* pack = (uint2*)(ws + o_pack);

        hipMemsetAsync(cnt, 0, (size_t)NBT * CURS * 4, stream);

        hist_buckets<<<256, 256, 0, stream>>>(
            u_rows, nnz_u, i_rows, nnz_i, f_rows, nnz_f, cnt);

        scan_buckets<<<1, 256, 0, stream>>>(cnt, bptr);

        scatter_buckets<<<eblocks(nnz_tot), 256, 0, stream>>>(
            u_rows, u_cols, u_vals, nnz_u,
            i_rows, i_cols, i_vals, nnz_i,
            f_rows, f_cols, f_vals, nnz_f,
            cnt, pack);

        // u + i gathers (one launch, one block per bucket)
        gather_buckets<<<NBU + NBI, 256, 0, stream>>>(
            bptr, pack,
            (const float4*)user_emb, um, NBU, 32, N_GROUPS, 0,
            (const float4*)item_emb, im, 16, N_GROUPS, NBU);

        dense_agg<<<(N_GROUPS + 31) / 32, 256, 0, stream>>>(um, im, W, bias, msg);

        // f gather -> norm (overwrites scratch region)
        gather_buckets<<<NBF, 256, 0, stream>>>(
            bptr, pack,
            (const float4*)msg, norm, NBF, 64, N_FULL, NBU + NBI,
            (const float4*)msg, norm, 64, N_FULL, NBU + NBI);
    } else {
        // Fallback: R1 atomic path
        hipMemsetAsync(norm, 0, (size_t)N_FULL * DIM * sizeof(float), stream);
        auto spmm_blocks = [](int nnz) {
            return (unsigned)(((long long)nnz * 32 + 255) / 256);
        };
        spmm_atomic<<<spmm_blocks(nnz_u), 256, 0, stream>>>(
            u_rows, u_cols, u_vals, user_emb, um, nnz_u);
        spmm_atomic<<<spmm_blocks(nnz_i), 256, 0, stream>>>(
            i_rows, i_cols, i_vals, item_emb, im, nnz_i);
        dense_agg<<<(N_GROUPS + 31) / 32, 256, 0, stream>>>(um, im, W, bias, msg);
        hipMemsetAsync(norm, 0, (size_t)2 * N_GROUPS * DIM * sizeof(float), stream);
        spmm_atomic<<<spmm_blocks(nnz_f), 256, 0, stream>>>(
            f_rows, f_cols, f_vals, msg, norm, nnz_f);
    }
}